// Round 6
// baseline (282.437 us; speedup 1.0000x reference)
//
#include <hip/hip_runtime.h>
#include <math.h>

// ---------------------------------------------------------------------------
// PPFNet pipeline on MI355X. B=16 clouds x 2048 pts, K=16 knn, all f32.
// 3 launches:
//  K1 knn_conv1 : block = 512 = 32 points x 16 slices (100% occupancy:
//     35.5KB LDS -> 4 blocks/CU x 8 waves = 32 waves/CU; VGPR capped 64
//     via __launch_bounds__(512,8)).
//     A: med3 top-4/slice of s=|c|^2-2p.c; B: shuffle bitonic -> tau;
//     C: rescan collect; D: exact-d2 fixup; E: nbr+ppf (poly atan2);
//     fused conv1 (edge-local) + gfromh (node-local) -> writes nbr, ppf, G.
//  K2 conv2_pool: 1 edge/thread: relu(G[j] + ppf@W2a[32:36]) -> 32x32 ->
//     16-lane shfl max -> chunk results straight to LDS -> block reduce ->
//     int atomicMax per cloud (h2>=0 so int-compare is order-preserving;
//     0xAA poison is negative = identity).
//  K3 fc        : per-cloud Linear(32,40).
// ---------------------------------------------------------------------------

#define NPER 2048
#define NCLOUD 16

// ws layout (bytes)
#define OFF_NBR  (size_t)(0u)          // int   [N][16]    (2 MB)
#define OFF_PPF  (size_t)(2u << 20)    // float [N][16][4] (8 MB)
#define OFF_G    (size_t)(10u << 20)   // float [N][32]    (4 MB)
#define OFF_POOL (size_t)(14u << 20)   // int   [16][32]   (2 KB)

__device__ __forceinline__ float med3(float a, float b, float c) {
    return __builtin_amdgcn_fmed3f(a, b, c);
}
__device__ __forceinline__ void cex(float& a, float& b) {
    const float lo = fminf(a, b), hi = fmaxf(a, b); a = lo; b = hi;
}
__device__ __forceinline__ void bmerge8(float (&v)[8]) {
#pragma unroll
    for (int i = 0; i < 4; ++i) cex(v[i], v[i + 4]);
#pragma unroll
    for (int b = 0; b < 8; b += 4)
#pragma unroll
        for (int i = 0; i < 2; ++i) cex(v[b + i], v[b + i + 2]);
#pragma unroll
    for (int b = 0; b < 8; b += 2) cex(v[b], v[b + 1]);
}
__device__ __forceinline__ void bmerge16(float (&v)[16]) {
#pragma unroll
    for (int i = 0; i < 8; ++i) cex(v[i], v[i + 8]);
#pragma unroll
    for (int b = 0; b < 16; b += 8)
#pragma unroll
        for (int i = 0; i < 4; ++i) cex(v[b + i], v[b + i + 4]);
#pragma unroll
    for (int b = 0; b < 16; b += 4)
#pragma unroll
        for (int i = 0; i < 2; ++i) cex(v[b + i], v[b + i + 2]);
#pragma unroll
    for (int b = 0; b < 16; b += 2) cex(v[b], v[b + 1]);
}

// atan2(y,x) with y >= 0, range [0,pi]. A&S 4.4.49 poly, err ~1e-6 rad
// (output tolerance is 4.57e-3 - amplification through the MLPs is ~O(1)).
__device__ __forceinline__ float fast_atan2p(float y, float x) {
    const float ax = fabsf(x);
    const float mn = fminf(ax, y), mx = fmaxf(ax, y);
    float a = mn * __builtin_amdgcn_rcpf(mx);
    a = (mx == 0.f) ? 0.f : a;
    const float t = a * a;
    float p = fmaf(t, 0.0028662257f, -0.0161657367f);
    p = fmaf(t, p, 0.0429096138f);
    p = fmaf(t, p, -0.0752896400f);
    p = fmaf(t, p, 0.1065626393f);
    p = fmaf(t, p, -0.1420889944f);
    p = fmaf(t, p, 0.1999355085f);
    p = fmaf(t, p, -0.3333314528f);
    float r = fmaf(a * t, p, a);                 // atan(a), a in [0,1]
    r = (y > ax) ? (1.5707963268f - r) : r;
    r = (x < 0.f) ? (3.1415926536f - r) : r;
    return r;
}

__device__ __forceinline__ float angf(float ax, float ay, float az,
                                      float bx, float by, float bz) {
    const float cx = ay * bz - az * by;
    const float cy = az * bx - ax * bz;
    const float cz = ax * by - ay * bx;
    const float cn = sqrtf(cx * cx + cy * cy + cz * cz);
    const float dt = ax * bx + ay * by + az * bz;
    return fast_atan2p(cn, dt);
}

// ---------------------------------------------------------------------------
// K1: knn + ppf + conv1 + gfromh. Block = 512 = 32 points x 16 slices.
// Grid = 1024. LDS ~35.5 KB -> 4 blocks/CU x 8 waves = 32 waves/CU.
// ---------------------------------------------------------------------------
__global__ __launch_bounds__(512, 8) void knn_conv1(const float* __restrict__ pos,
                                                    const float* __restrict__ nrm,
                                                    const float* __restrict__ W1a,
                                                    const float* __restrict__ b1a,
                                                    const float* __restrict__ W1b,
                                                    const float* __restrict__ b1b,
                                                    const float* __restrict__ W2a,
                                                    const float* __restrict__ b2a,
                                                    int* __restrict__ nbr,
                                                    float* __restrict__ ppf,
                                                    float* __restrict__ G) {
    const int tid = threadIdx.x;
    const int pl  = tid >> 4;               // point within block (0..31)
    const int sl  = tid & 15;               // slice / lane-in-node (0..15)
    const int gp  = blockIdx.x * 32 + pl;   // global point
    const int cloud = gp >> 11;
    const int lp  = gp & 2047;              // local point idx in cloud
    const int cbase = cloud * NPER;

    __shared__ float4 tile[2048];           // x,y,z,|c|^2  (32 KB)
    __shared__ unsigned short hiL[32][40];  // hit local indices (2.5 KB)
    __shared__ int cnt[32];

    if (tid < 32) cnt[tid] = 0;

#pragma unroll
    for (int c = 0; c < 4; ++c) {
        const int idx = c * 512 + tid;
        const float x = pos[(cbase + idx) * 3 + 0];
        const float y = pos[(cbase + idx) * 3 + 1];
        const float z = pos[(cbase + idx) * 3 + 2];
        tile[idx] = make_float4(x, y, z, x * x + y * y + z * z);
    }
    __syncthreads();

    const float4 P  = tile[lp];
    const float pn2 = P.w;
    const float m2x = -2.f * P.x, m2y = -2.f * P.y, m2z = -2.f * P.z;

    // ---- Phase A: top-4 of s per slice (128 candidates), branchless ----
    float dl[4];
#pragma unroll
    for (int m = 0; m < 4; ++m) dl[m] = INFINITY;

#pragma unroll 4
    for (int jj = 0; jj < 128; ++jj) {
        const int cand = jj * 16 + sl;
        const float4 C = tile[cand];
        float s = fmaf(m2x, C.x, fmaf(m2y, C.y, fmaf(m2z, C.z, C.w)));
        s = (cand == lp) ? INFINITY : s;
        dl[3] = med3(dl[2], dl[3], s);
        dl[2] = med3(dl[1], dl[2], s);
        dl[1] = med3(dl[0], dl[1], s);
        dl[0] = fminf(dl[0], s);
    }

    // ---- Phase B: shuffle bitonic merge of 16 sorted-4 lists -> tau ----
    float tau_s;
    {
        float v8[8];
#pragma unroll
        for (int i = 0; i < 4; ++i) v8[i] = dl[i];
#pragma unroll
        for (int i = 0; i < 4; ++i) v8[7 - i] = __shfl_xor(dl[i], 1);
        bmerge8(v8);
        float v[16];
#pragma unroll
        for (int i = 0; i < 8; ++i) v[i] = v8[i];
#pragma unroll
        for (int i = 0; i < 8; ++i) v[15 - i] = __shfl_xor(v8[i], 2);
        bmerge16(v);
        {
            float p[16];
#pragma unroll
            for (int i = 0; i < 16; ++i) p[i] = __shfl_xor(v[i], 4);
            float w[16];
#pragma unroll
            for (int i = 0; i < 16; ++i) w[i] = fminf(v[i], p[15 - i]);
            bmerge16(w);
#pragma unroll
            for (int i = 0; i < 16; ++i) v[i] = w[i];
        }
        {
            float p[16];
#pragma unroll
            for (int i = 0; i < 16; ++i) p[i] = __shfl_xor(v[i], 8);
            float t = -INFINITY;
#pragma unroll
            for (int i = 0; i < 16; ++i) t = fmaxf(t, fminf(v[i], p[15 - i]));
            tau_s = t;
        }
    }
    const float tsw = tau_s + 6e-5f * (1.f + pn2 + fabsf(tau_s + pn2));

    // ---- Phase C: rescan on s, collect hit indices ----
#pragma unroll 4
    for (int jj = 0; jj < 128; ++jj) {
        const int cand = jj * 16 + sl;
        const float4 C = tile[cand];
        const float s = fmaf(m2x, C.x, fmaf(m2y, C.y, fmaf(m2z, C.z, C.w)));
        if (s <= tsw && cand != lp) {
            const int k = atomicAdd(&cnt[pl], 1);
            if (k < 40) hiL[pl][k] = (unsigned short)cand;
        }
    }
    __syncthreads();

    // ---- Phase D: exact top-16 (bit-identical d2, index tiebreak) ----
    if (tid < 32) {
        int n = cnt[tid];
        n = n > 40 ? 40 : n;
        if (n != 16) {
            const int myl = (blockIdx.x * 32 + tid) & 2047;
            const float4 Q = tile[myl];
            unsigned long long keys[16];
#pragma unroll
            for (int m = 0; m < 16; ++m) keys[m] = ~0ULL;
            for (int i = 0; i < n; ++i) {
                const int cand = hiL[tid][i];
                const float4 C = tile[cand];
                const float dx = __fsub_rn(Q.x, C.x);
                const float dy = __fsub_rn(Q.y, C.y);
                const float dz = __fsub_rn(Q.z, C.z);
                const float d2 = __fadd_rn(__fadd_rn(__fmul_rn(dx, dx),
                                                     __fmul_rn(dy, dy)),
                                           __fmul_rn(dz, dz));
                const unsigned long long key =
                    ((unsigned long long)__float_as_uint(d2) << 32) |
                    (unsigned int)cand;
                if (key < keys[15]) {
#pragma unroll
                    for (int m = 15; m >= 1; --m) {
                        const bool up   = key < keys[m - 1];
                        const bool here = key < keys[m];
                        keys[m] = up ? keys[m - 1] : (here ? key : keys[m]);
                    }
                    if (key < keys[0]) keys[0] = key;
                }
            }
#pragma unroll
            for (int m = 0; m < 16; ++m)
                hiL[tid][m] = (unsigned short)(keys[m] & 0xFFFFu);
        }
    }
    __syncthreads();

    // ---- Phase E: nbr + ppf (1 edge per thread, ppf kept in regs) ----
    const float nix = nrm[gp * 3 + 0], niy = nrm[gp * 3 + 1], niz = nrm[gp * 3 + 2];
    float4 x;
    {
        const int jl = hiL[pl][sl];
        const int j  = cbase + jl;
        nbr[gp * 16 + sl] = j;
        const float4 C = tile[jl];
        const float njx = nrm[j * 3 + 0], njy = nrm[j * 3 + 1], njz = nrm[j * 3 + 2];
        const float dx = C.x - P.x, dy = C.y - P.y, dz = C.z - P.z;
        x.x = sqrtf(dx * dx + dy * dy + dz * dz);
        x.y = angf(nix, niy, niz, dx, dy, dz);
        x.z = angf(njx, njy, njz, dx, dy, dz);
        x.w = angf(nix, niy, niz, njx, njy, njz);
        ((float4*)ppf)[(size_t)gp * 16 + sl] = x;
    }

    // ---- FUSED conv1: layer1 (4->32) on this edge ----
    float h1[32];
#pragma unroll
    for (int o = 0; o < 32; ++o) {
        h1[o] = fmaxf(fmaf(x.x, W1a[o],
                     fmaf(x.y, W1a[32 + o],
                     fmaf(x.z, W1a[64 + o],
                     fmaf(x.w, W1a[96 + o], b1a[o])))), 0.f);
    }

    // ---- layer2 (32->32) in 4x8 chunks + 16-lane max; all lanes keep h ----
    float hr[32];
#pragma unroll 1
    for (int ob = 0; ob < 4; ++ob) {
        float acc[8];
#pragma unroll
        for (int u = 0; u < 8; ++u) acc[u] = b1b[ob * 8 + u];
#pragma unroll
        for (int hh = 0; hh < 32; ++hh) {
            const float hv = h1[hh];
#pragma unroll
            for (int u = 0; u < 8; ++u)
                acc[u] = fmaf(hv, W1b[hh * 32 + ob * 8 + u], acc[u]);
        }
#pragma unroll
        for (int u = 0; u < 8; ++u) {
            float v = acc[u];
            v = fmaxf(v, __shfl_xor(v, 1));
            v = fmaxf(v, __shfl_xor(v, 2));
            v = fmaxf(v, __shfl_xor(v, 4));
            v = fmaxf(v, __shfl_xor(v, 8));
            hr[ob * 8 + u] = fmaxf(v, 0.f);
        }
    }

    // ---- FUSED gfromh: G[node] = hr @ W2a[0:32,:] + b2a (2 cols/lane) ----
    {
        const int c0 = sl * 2;
        float g0 = b2a[c0], g1 = b2a[c0 + 1];
#pragma unroll
        for (int k = 0; k < 32; ++k) {
            g0 = fmaf(hr[k], W2a[k * 32 + c0], g0);
            g1 = fmaf(hr[k], W2a[k * 32 + c0 + 1], g1);
        }
        ((float2*)(G + (size_t)gp * 32))[sl] = make_float2(g0, g1);
    }
}

// ---------------------------------------------------------------------------
// K2: conv2 + pool. 1 edge/thread, 16 threads/node, block = 16 nodes.
// Grid 2048 x 256. Chunk results go straight to LDS (no h2r regs).
// ---------------------------------------------------------------------------
__global__ __launch_bounds__(256, 8) void conv2_pool(const float* __restrict__ ppf,
                                                     const int* __restrict__ nbr,
                                                     const float* __restrict__ G,
                                                     const float* __restrict__ W2a,
                                                     const float* __restrict__ W2b,
                                                     const float* __restrict__ b2b,
                                                     int* __restrict__ pooledi) {
    const int tid    = threadIdx.x;
    const int gid    = blockIdx.x * 256 + tid;    // edge id
    const int node16 = tid >> 4;                  // node within block
    const int cloud  = blockIdx.x >> 7;           // 128 blocks per cloud

    const int j = nbr[gid];

    float h1[32];
    {
        const float4* gr = (const float4*)(G + (size_t)j * 32);
#pragma unroll
        for (int q = 0; q < 8; ++q) {
            const float4 v = gr[q];
            h1[q * 4 + 0] = v.x; h1[q * 4 + 1] = v.y;
            h1[q * 4 + 2] = v.z; h1[q * 4 + 3] = v.w;
        }
    }
    const float4 x = ((const float4*)ppf)[gid];
#pragma unroll
    for (int o = 0; o < 32; ++o) {
        h1[o] = fmaxf(fmaf(x.x, W2a[32 * 32 + o],
                     fmaf(x.y, W2a[33 * 32 + o],
                     fmaf(x.z, W2a[34 * 32 + o],
                     fmaf(x.w, W2a[35 * 32 + o], h1[o])))), 0.f);
    }

    __shared__ float sh[16][33];
#pragma unroll 1
    for (int ob = 0; ob < 4; ++ob) {
        float acc[8];
#pragma unroll
        for (int u = 0; u < 8; ++u) acc[u] = b2b[ob * 8 + u];
#pragma unroll
        for (int hh = 0; hh < 32; ++hh) {
            const float hv = h1[hh];
#pragma unroll
            for (int u = 0; u < 8; ++u)
                acc[u] = fmaf(hv, W2b[hh * 32 + ob * 8 + u], acc[u]);
        }
#pragma unroll
        for (int u = 0; u < 8; ++u) {
            float v = acc[u];
            v = fmaxf(v, __shfl_xor(v, 1));
            v = fmaxf(v, __shfl_xor(v, 2));
            v = fmaxf(v, __shfl_xor(v, 4));
            v = fmaxf(v, __shfl_xor(v, 8));
            if ((tid & 15) == 0) sh[node16][ob * 8 + u] = fmaxf(v, 0.f);
        }
    }
    __syncthreads();

    if (tid < 32) {
        float m = sh[0][tid];
#pragma unroll
        for (int n = 1; n < 16; ++n) m = fmaxf(m, sh[n][tid]);
        atomicMax(&pooledi[cloud * 32 + tid], __float_as_int(m));
    }
}

// ---------------------------------------------------------------------------
// K3: fc. Grid 16 x 64. out[b][c] = bc[c] + pooled[b] . Wc[:,c]
// ---------------------------------------------------------------------------
__global__ __launch_bounds__(64) void fc_kernel(const int* __restrict__ pooledi,
                                                const float* __restrict__ Wc,
                                                const float* __restrict__ bc,
                                                float* __restrict__ out) {
    const int b = blockIdx.x;
    const int tid = threadIdx.x;
    if (tid < 40) {
        float acc = bc[tid];
#pragma unroll
        for (int o = 0; o < 32; ++o)
            acc = fmaf(__int_as_float(pooledi[b * 32 + o]), Wc[o * 40 + tid], acc);
        out[b * 40 + tid] = acc;
    }
}

// ---------------------------------------------------------------------------
extern "C" void kernel_launch(void* const* d_in, const int* in_sizes, int n_in,
                              void* d_out, int out_size, void* d_ws, size_t ws_size,
                              hipStream_t stream) {
    const float* pos = (const float*)d_in[0];
    const float* nrm = (const float*)d_in[1];
    const float* W1a = (const float*)d_in[3];
    const float* b1a = (const float*)d_in[4];
    const float* W1b = (const float*)d_in[5];
    const float* b1b = (const float*)d_in[6];
    const float* W2a = (const float*)d_in[7];
    const float* b2a = (const float*)d_in[8];
    const float* W2b = (const float*)d_in[9];
    const float* b2b = (const float*)d_in[10];
    const float* Wc  = (const float*)d_in[11];
    const float* bc  = (const float*)d_in[12];
    float* out = (float*)d_out;

    char* ws = (char*)d_ws;
    int*   nbr = (int*)(ws + OFF_NBR);
    float* ppf = (float*)(ws + OFF_PPF);
    float* G   = (float*)(ws + OFF_G);
    int*   pli = (int*)(ws + OFF_POOL);

    hipLaunchKernelGGL(knn_conv1,  dim3(1024), dim3(512), 0, stream,
                       pos, nrm, W1a, b1a, W1b, b1b, W2a, b2a, nbr, ppf, G);
    hipLaunchKernelGGL(conv2_pool, dim3(2048), dim3(256), 0, stream,
                       ppf, nbr, G, W2a, W2b, b2b, pli);
    hipLaunchKernelGGL(fc_kernel,  dim3(16),   dim3(64),  0, stream,
                       pli, Wc, bc, out);
}

// Round 7
// 270.545 us; speedup vs baseline: 1.0440x; 1.0440x over previous
//
#include <hip/hip_runtime.h>
#include <math.h>

// ---------------------------------------------------------------------------
// PPFNet pipeline on MI355X. B=16 clouds x 2048 pts, K=16 knn, all f32.
// 3 launches.
// NOTE: round-6 lesson — __launch_bounds__ second arg > 4 made the allocator
// target ~32 VGPRs, spilling the h1[32]/hr[32] working set to scratch
// (VALUBusy 67%->2.4%, WRITE_SIZE 14->78MB). Keep plain bounds / ,4 only.
//  K1 knn_conv1 : block = 256 = 16 points x 16 slices; whole cloud in LDS.
//     A: med3 top-4/slice of s=|c|^2-2p.c; B: shuffle bitonic -> tau;
//     C: rescan collect; D: exact-d2 fixup; E: nbr+ppf (poly atan2);
//     fused conv1 (edge-local) + gfromh (node-local) -> writes nbr, ppf, G.
//  K2 conv2_pool: 1 edge/thread: relu(G[j] + ppf@W2a[32:36]) -> 32x32 ->
//     16-lane shfl max -> block reduce -> int atomicMax per cloud
//     (h2>=0 so int-compare is order-preserving; 0xAA poison negative =
//      identity for the max).
//  K3 fc        : per-cloud Linear(32,40).
// ---------------------------------------------------------------------------

#define NPER 2048
#define NCLOUD 16

// ws layout (bytes)
#define OFF_NBR  (size_t)(0u)          // int   [N][16]    (2 MB)
#define OFF_PPF  (size_t)(2u << 20)    // float [N][16][4] (8 MB)
#define OFF_G    (size_t)(10u << 20)   // float [N][32]    (4 MB)
#define OFF_POOL (size_t)(14u << 20)   // int   [16][32]   (2 KB)

__device__ __forceinline__ float med3(float a, float b, float c) {
    return __builtin_amdgcn_fmed3f(a, b, c);
}
__device__ __forceinline__ void cex(float& a, float& b) {
    const float lo = fminf(a, b), hi = fmaxf(a, b); a = lo; b = hi;
}
__device__ __forceinline__ void bmerge8(float (&v)[8]) {
#pragma unroll
    for (int i = 0; i < 4; ++i) cex(v[i], v[i + 4]);
#pragma unroll
    for (int b = 0; b < 8; b += 4)
#pragma unroll
        for (int i = 0; i < 2; ++i) cex(v[b + i], v[b + i + 2]);
#pragma unroll
    for (int b = 0; b < 8; b += 2) cex(v[b], v[b + 1]);
}
__device__ __forceinline__ void bmerge16(float (&v)[16]) {
#pragma unroll
    for (int i = 0; i < 8; ++i) cex(v[i], v[i + 8]);
#pragma unroll
    for (int b = 0; b < 16; b += 8)
#pragma unroll
        for (int i = 0; i < 4; ++i) cex(v[b + i], v[b + i + 4]);
#pragma unroll
    for (int b = 0; b < 16; b += 4)
#pragma unroll
        for (int i = 0; i < 2; ++i) cex(v[b + i], v[b + i + 2]);
#pragma unroll
    for (int b = 0; b < 16; b += 2) cex(v[b], v[b + 1]);
}

// atan2(y,x) with y >= 0, range [0,pi]. A&S 4.4.49 poly, err ~1e-6 rad
// (output tolerance 4.57e-3; MLP amplification ~O(1)).
__device__ __forceinline__ float fast_atan2p(float y, float x) {
    const float ax = fabsf(x);
    const float mn = fminf(ax, y), mx = fmaxf(ax, y);
    float a = mn * __builtin_amdgcn_rcpf(mx);
    a = (mx == 0.f) ? 0.f : a;
    const float t = a * a;
    float p = fmaf(t, 0.0028662257f, -0.0161657367f);
    p = fmaf(t, p, 0.0429096138f);
    p = fmaf(t, p, -0.0752896400f);
    p = fmaf(t, p, 0.1065626393f);
    p = fmaf(t, p, -0.1420889944f);
    p = fmaf(t, p, 0.1999355085f);
    p = fmaf(t, p, -0.3333314528f);
    float r = fmaf(a * t, p, a);                 // atan(a), a in [0,1]
    r = (y > ax) ? (1.5707963268f - r) : r;
    r = (x < 0.f) ? (3.1415926536f - r) : r;
    return r;
}

__device__ __forceinline__ float angf(float ax, float ay, float az,
                                      float bx, float by, float bz) {
    const float cx = ay * bz - az * by;
    const float cy = az * bx - ax * bz;
    const float cz = ax * by - ay * bx;
    const float cn = sqrtf(cx * cx + cy * cy + cz * cz);
    const float dt = ax * bx + ay * by + az * bz;
    return fast_atan2p(cn, dt);
}

// ---------------------------------------------------------------------------
// K1: knn + ppf + conv1 + gfromh. Block = 256 = 16 points x 16 slices.
// Grid = 2048. LDS ~33.5 KB -> 4 blocks/CU x 4 waves = 16 waves/CU.
// ---------------------------------------------------------------------------
__global__ __launch_bounds__(256) void knn_conv1(const float* __restrict__ pos,
                                                 const float* __restrict__ nrm,
                                                 const float* __restrict__ W1a,
                                                 const float* __restrict__ b1a,
                                                 const float* __restrict__ W1b,
                                                 const float* __restrict__ b1b,
                                                 const float* __restrict__ W2a,
                                                 const float* __restrict__ b2a,
                                                 int* __restrict__ nbr,
                                                 float* __restrict__ ppf,
                                                 float* __restrict__ G) {
    const int tid = threadIdx.x;
    const int pl  = tid >> 4;               // point within block (0..15)
    const int sl  = tid & 15;               // slice / lane-in-node (0..15)
    const int gp  = blockIdx.x * 16 + pl;   // global point
    const int cloud = gp >> 11;
    const int lp  = gp & 2047;              // local point idx in cloud
    const int cbase = cloud * NPER;

    __shared__ float4 tile[2048];           // x,y,z,|c|^2  (32 KB)
    __shared__ unsigned short hiL[16][40];  // hit local indices (1.25 KB)
    __shared__ int cnt[16];

    if (tid < 16) cnt[tid] = 0;

#pragma unroll
    for (int c = 0; c < 8; ++c) {
        const int idx = c * 256 + tid;
        const float x = pos[(cbase + idx) * 3 + 0];
        const float y = pos[(cbase + idx) * 3 + 1];
        const float z = pos[(cbase + idx) * 3 + 2];
        tile[idx] = make_float4(x, y, z, x * x + y * y + z * z);
    }
    __syncthreads();

    const float4 P  = tile[lp];
    const float pn2 = P.w;
    const float m2x = -2.f * P.x, m2y = -2.f * P.y, m2z = -2.f * P.z;

    // ---- Phase A: top-4 of s per slice (128 candidates), branchless ----
    float dl[4];
#pragma unroll
    for (int m = 0; m < 4; ++m) dl[m] = INFINITY;

#pragma unroll 4
    for (int jj = 0; jj < 128; ++jj) {
        const int cand = jj * 16 + sl;
        const float4 C = tile[cand];
        float s = fmaf(m2x, C.x, fmaf(m2y, C.y, fmaf(m2z, C.z, C.w)));
        s = (cand == lp) ? INFINITY : s;
        dl[3] = med3(dl[2], dl[3], s);
        dl[2] = med3(dl[1], dl[2], s);
        dl[1] = med3(dl[0], dl[1], s);
        dl[0] = fminf(dl[0], s);
    }

    // ---- Phase B: shuffle bitonic merge of 16 sorted-4 lists -> tau ----
    float tau_s;
    {
        float v8[8];
#pragma unroll
        for (int i = 0; i < 4; ++i) v8[i] = dl[i];
#pragma unroll
        for (int i = 0; i < 4; ++i) v8[7 - i] = __shfl_xor(dl[i], 1);
        bmerge8(v8);
        float v[16];
#pragma unroll
        for (int i = 0; i < 8; ++i) v[i] = v8[i];
#pragma unroll
        for (int i = 0; i < 8; ++i) v[15 - i] = __shfl_xor(v8[i], 2);
        bmerge16(v);
        {
            float p[16];
#pragma unroll
            for (int i = 0; i < 16; ++i) p[i] = __shfl_xor(v[i], 4);
            float w[16];
#pragma unroll
            for (int i = 0; i < 16; ++i) w[i] = fminf(v[i], p[15 - i]);
            bmerge16(w);
#pragma unroll
            for (int i = 0; i < 16; ++i) v[i] = w[i];
        }
        {
            float p[16];
#pragma unroll
            for (int i = 0; i < 16; ++i) p[i] = __shfl_xor(v[i], 8);
            float t = -INFINITY;
#pragma unroll
            for (int i = 0; i < 16; ++i) t = fmaxf(t, fminf(v[i], p[15 - i]));
            tau_s = t;
        }
    }
    const float tsw = tau_s + 6e-5f * (1.f + pn2 + fabsf(tau_s + pn2));

    // ---- Phase C: rescan on s, collect hit indices ----
#pragma unroll 4
    for (int jj = 0; jj < 128; ++jj) {
        const int cand = jj * 16 + sl;
        const float4 C = tile[cand];
        const float s = fmaf(m2x, C.x, fmaf(m2y, C.y, fmaf(m2z, C.z, C.w)));
        if (s <= tsw && cand != lp) {
            const int k = atomicAdd(&cnt[pl], 1);
            if (k < 40) hiL[pl][k] = (unsigned short)cand;
        }
    }
    __syncthreads();

    // ---- Phase D: exact top-16 (bit-identical d2, index tiebreak) ----
    if (tid < 16) {
        int n = cnt[tid];
        n = n > 40 ? 40 : n;
        if (n != 16) {
            const int myl = (blockIdx.x * 16 + tid) & 2047;
            const float4 Q = tile[myl];
            unsigned long long keys[16];
#pragma unroll
            for (int m = 0; m < 16; ++m) keys[m] = ~0ULL;
            for (int i = 0; i < n; ++i) {
                const int cand = hiL[tid][i];
                const float4 C = tile[cand];
                const float dx = __fsub_rn(Q.x, C.x);
                const float dy = __fsub_rn(Q.y, C.y);
                const float dz = __fsub_rn(Q.z, C.z);
                const float d2 = __fadd_rn(__fadd_rn(__fmul_rn(dx, dx),
                                                     __fmul_rn(dy, dy)),
                                           __fmul_rn(dz, dz));
                const unsigned long long key =
                    ((unsigned long long)__float_as_uint(d2) << 32) |
                    (unsigned int)cand;
                if (key < keys[15]) {
#pragma unroll
                    for (int m = 15; m >= 1; --m) {
                        const bool up   = key < keys[m - 1];
                        const bool here = key < keys[m];
                        keys[m] = up ? keys[m - 1] : (here ? key : keys[m]);
                    }
                    if (key < keys[0]) keys[0] = key;
                }
            }
#pragma unroll
            for (int m = 0; m < 16; ++m)
                hiL[tid][m] = (unsigned short)(keys[m] & 0xFFFFu);
        }
    }
    __syncthreads();

    // ---- Phase E: nbr + ppf (1 edge per thread, ppf kept in regs) ----
    const float nix = nrm[gp * 3 + 0], niy = nrm[gp * 3 + 1], niz = nrm[gp * 3 + 2];
    float4 x;
    {
        const int jl = hiL[pl][sl];
        const int j  = cbase + jl;
        nbr[gp * 16 + sl] = j;
        const float4 C = tile[jl];
        const float njx = nrm[j * 3 + 0], njy = nrm[j * 3 + 1], njz = nrm[j * 3 + 2];
        const float dx = C.x - P.x, dy = C.y - P.y, dz = C.z - P.z;
        x.x = sqrtf(dx * dx + dy * dy + dz * dz);
        x.y = angf(nix, niy, niz, dx, dy, dz);
        x.z = angf(njx, njy, njz, dx, dy, dz);
        x.w = angf(nix, niy, niz, njx, njy, njz);
        ((float4*)ppf)[(size_t)gp * 16 + sl] = x;
    }

    // ---- FUSED conv1: layer1 (4->32) on this edge ----
    float h1[32];
#pragma unroll
    for (int o = 0; o < 32; ++o) {
        h1[o] = fmaxf(fmaf(x.x, W1a[o],
                     fmaf(x.y, W1a[32 + o],
                     fmaf(x.z, W1a[64 + o],
                     fmaf(x.w, W1a[96 + o], b1a[o])))), 0.f);
    }

    // ---- layer2 (32->32) in 4x8 chunks + 16-lane max; all lanes keep h ----
    float hr[32];
#pragma unroll 1
    for (int ob = 0; ob < 4; ++ob) {
        float acc[8];
#pragma unroll
        for (int u = 0; u < 8; ++u) acc[u] = b1b[ob * 8 + u];
#pragma unroll
        for (int hh = 0; hh < 32; ++hh) {
            const float hv = h1[hh];
#pragma unroll
            for (int u = 0; u < 8; ++u)
                acc[u] = fmaf(hv, W1b[hh * 32 + ob * 8 + u], acc[u]);
        }
#pragma unroll
        for (int u = 0; u < 8; ++u) {
            float v = acc[u];
            v = fmaxf(v, __shfl_xor(v, 1));
            v = fmaxf(v, __shfl_xor(v, 2));
            v = fmaxf(v, __shfl_xor(v, 4));
            v = fmaxf(v, __shfl_xor(v, 8));
            hr[ob * 8 + u] = fmaxf(v, 0.f);
        }
    }

    // ---- FUSED gfromh: G[node] = hr @ W2a[0:32,:] + b2a (2 cols/lane) ----
    {
        const int c0 = sl * 2;
        float g0 = b2a[c0], g1 = b2a[c0 + 1];
#pragma unroll
        for (int k = 0; k < 32; ++k) {
            g0 = fmaf(hr[k], W2a[k * 32 + c0], g0);
            g1 = fmaf(hr[k], W2a[k * 32 + c0 + 1], g1);
        }
        ((float2*)(G + (size_t)gp * 32))[sl] = make_float2(g0, g1);
    }
}

// ---------------------------------------------------------------------------
// K2: conv2 + pool. 1 edge/thread, 16 threads/node, block = 16 nodes.
// Grid 2048 x 256. (256,4): VGPR budget 128 - fits h1[32]+acc[8] w/o spill.
// ---------------------------------------------------------------------------
__global__ __launch_bounds__(256, 4) void conv2_pool(const float* __restrict__ ppf,
                                                     const int* __restrict__ nbr,
                                                     const float* __restrict__ G,
                                                     const float* __restrict__ W2a,
                                                     const float* __restrict__ W2b,
                                                     const float* __restrict__ b2b,
                                                     int* __restrict__ pooledi) {
    const int tid    = threadIdx.x;
    const int gid    = blockIdx.x * 256 + tid;    // edge id
    const int node16 = tid >> 4;                  // node within block
    const int cloud  = blockIdx.x >> 7;           // 128 blocks per cloud

    const int j = nbr[gid];

    float h1[32];
    {
        const float4* gr = (const float4*)(G + (size_t)j * 32);
#pragma unroll
        for (int q = 0; q < 8; ++q) {
            const float4 v = gr[q];
            h1[q * 4 + 0] = v.x; h1[q * 4 + 1] = v.y;
            h1[q * 4 + 2] = v.z; h1[q * 4 + 3] = v.w;
        }
    }
    const float4 x = ((const float4*)ppf)[gid];
#pragma unroll
    for (int o = 0; o < 32; ++o) {
        h1[o] = fmaxf(fmaf(x.x, W2a[32 * 32 + o],
                     fmaf(x.y, W2a[33 * 32 + o],
                     fmaf(x.z, W2a[34 * 32 + o],
                     fmaf(x.w, W2a[35 * 32 + o], h1[o])))), 0.f);
    }

    __shared__ float sh[16][33];
#pragma unroll 1
    for (int ob = 0; ob < 4; ++ob) {
        float acc[8];
#pragma unroll
        for (int u = 0; u < 8; ++u) acc[u] = b2b[ob * 8 + u];
#pragma unroll
        for (int hh = 0; hh < 32; ++hh) {
            const float hv = h1[hh];
#pragma unroll
            for (int u = 0; u < 8; ++u)
                acc[u] = fmaf(hv, W2b[hh * 32 + ob * 8 + u], acc[u]);
        }
#pragma unroll
        for (int u = 0; u < 8; ++u) {
            float v = acc[u];
            v = fmaxf(v, __shfl_xor(v, 1));
            v = fmaxf(v, __shfl_xor(v, 2));
            v = fmaxf(v, __shfl_xor(v, 4));
            v = fmaxf(v, __shfl_xor(v, 8));
            if ((tid & 15) == 0) sh[node16][ob * 8 + u] = fmaxf(v, 0.f);
        }
    }
    __syncthreads();

    if (tid < 32) {
        float m = sh[0][tid];
#pragma unroll
        for (int n = 1; n < 16; ++n) m = fmaxf(m, sh[n][tid]);
        atomicMax(&pooledi[cloud * 32 + tid], __float_as_int(m));
    }
}

// ---------------------------------------------------------------------------
// K3: fc. Grid 16 x 64. out[b][c] = bc[c] + pooled[b] . Wc[:,c]
// ---------------------------------------------------------------------------
__global__ __launch_bounds__(64) void fc_kernel(const int* __restrict__ pooledi,
                                                const float* __restrict__ Wc,
                                                const float* __restrict__ bc,
                                                float* __restrict__ out) {
    const int b = blockIdx.x;
    const int tid = threadIdx.x;
    if (tid < 40) {
        float acc = bc[tid];
#pragma unroll
        for (int o = 0; o < 32; ++o)
            acc = fmaf(__int_as_float(pooledi[b * 32 + o]), Wc[o * 40 + tid], acc);
        out[b * 40 + tid] = acc;
    }
}

// ---------------------------------------------------------------------------
extern "C" void kernel_launch(void* const* d_in, const int* in_sizes, int n_in,
                              void* d_out, int out_size, void* d_ws, size_t ws_size,
                              hipStream_t stream) {
    const float* pos = (const float*)d_in[0];
    const float* nrm = (const float*)d_in[1];
    const float* W1a = (const float*)d_in[3];
    const float* b1a = (const float*)d_in[4];
    const float* W1b = (const float*)d_in[5];
    const float* b1b = (const float*)d_in[6];
    const float* W2a = (const float*)d_in[7];
    const float* b2a = (const float*)d_in[8];
    const float* W2b = (const float*)d_in[9];
    const float* b2b = (const float*)d_in[10];
    const float* Wc  = (const float*)d_in[11];
    const float* bc  = (const float*)d_in[12];
    float* out = (float*)d_out;

    char* ws = (char*)d_ws;
    int*   nbr = (int*)(ws + OFF_NBR);
    float* ppf = (float*)(ws + OFF_PPF);
    float* G   = (float*)(ws + OFF_G);
    int*   pli = (int*)(ws + OFF_POOL);

    hipLaunchKernelGGL(knn_conv1,  dim3(2048), dim3(256), 0, stream,
                       pos, nrm, W1a, b1a, W1b, b1b, W2a, b2a, nbr, ppf, G);
    hipLaunchKernelGGL(conv2_pool, dim3(2048), dim3(256), 0, stream,
                       ppf, nbr, G, W2a, W2b, b2b, pli);
    hipLaunchKernelGGL(fc_kernel,  dim3(16),   dim3(64),  0, stream,
                       pli, Wc, bc, out);
}